// Round 7
// baseline (653.711 us; speedup 1.0000x reference)
//
#include <hip/hip_runtime.h>
#include <hip/hip_bf16.h>

#define SEQ   2048
#define INSZ  5760
#define NQ    4096
#define NKV   512
#define NQKV  5120
#define HQ    64
#define HKV   8
#define HD    64
#define HID   2880
#define HIDP  2944   // 23*128, padded rows for woT

typedef __attribute__((ext_vector_type(8))) short bf16x8;
typedef __attribute__((ext_vector_type(4))) float f32x4;
typedef __attribute__((ext_vector_type(16))) float f32x16;
typedef unsigned int u32;

__device__ __forceinline__ unsigned short f2bf(float x) {
  __hip_bfloat16 b = __float2bfloat16(x);
  return __builtin_bit_cast(unsigned short, b);
}
__device__ __forceinline__ float bf2f(unsigned short u) {
  return __bfloat162float(__builtin_bit_cast(__hip_bfloat16, u));
}
__device__ __forceinline__ float exp2_hw(float x) {
  float r;
  asm("v_exp_f32 %0, %1" : "=v"(r) : "v"(x));
  return r;
}
__device__ __forceinline__ u32 cvt_pk_bf16(float lo, float hi) {
  u32 r;
  asm("v_cvt_pk_bf16_f32 %0, %1, %2" : "=v"(r) : "v"(lo), "v"(hi));
  return r;
}

// ---------------- fp32 -> bf16 elementwise convert ----------------
__global__ void k_convert(const float* __restrict__ src, unsigned short* __restrict__ dst, int n) {
  int stride = gridDim.x * blockDim.x * 4;
  for (int idx = (blockIdx.x * blockDim.x + threadIdx.x) * 4; idx < n; idx += stride) {
    float4 v = *(const float4*)(src + idx);
    ushort4 o;
    o.x = f2bf(v.x); o.y = f2bf(v.y); o.z = f2bf(v.z); o.w = f2bf(v.w);
    *(ushort4*)(dst + idx) = o;
  }
}

// ---------------- transpose-convert: src fp32 [K][N] -> dst bf16 [N][K] ----------------
__global__ void k_tconv(const float* __restrict__ src, unsigned short* __restrict__ dst,
                        int K, int N) {
  __shared__ float tile[64][33];
  int k0 = blockIdx.x * 64, n0 = blockIdx.y * 32;
  int tid = threadIdx.x;
  int r = tid >> 5, c = tid & 31;
#pragma unroll
  for (int i = 0; i < 8; i++) {
    int row = i * 8 + r;
    tile[row][c] = (n0 + c < N) ? src[(size_t)(k0 + row) * N + n0 + c] : 0.f;
  }
  __syncthreads();
  int n = tid >> 3, kk = (tid & 7) * 8;
  union { u32 w[4]; bf16x8 v; } u;
#pragma unroll
  for (int j = 0; j < 4; j++)
    u.w[j] = cvt_pk_bf16(tile[kk + 2 * j][n], tile[kk + 2 * j + 1][n]);
  *(bf16x8*)(dst + (size_t)(n0 + n) * K + k0 + kk) = u.v;
}

// ---------------- 8-phase-class GEMM: 256x256 tile, BK=32, counted vmcnt, swizzled LDS ----
// C[M][N] = A[M][K] * BT[N][K]^T, bf16 out. 8 waves (2M x 4N), per-wave 128x64.
// LDS 64KB: [buf][A|B][256 rows][64B], swizzle byte ^= (row&3)<<4 (involution; staged via
// inverse-swizzled global source, read via swizzled offset).
__global__ __launch_bounds__(512, 2) void k_gemm8(
    const unsigned short* __restrict__ A,   // M x K bf16
    const unsigned short* __restrict__ BT,  // N x K bf16
    unsigned short* __restrict__ C, int Kd, int ldc) {
  __shared__ __align__(16) char smem[65536];
  int tid = threadIdx.x, wid = tid >> 6, lane = tid & 63;
  int wr = wid >> 2, wc = wid & 3;
  // bijective XCD swizzle (nwg % 8 == 0)
  int nwg = gridDim.x * gridDim.y;
  int lin = blockIdx.y * gridDim.x + blockIdx.x;
  int qn = nwg >> 3;
  int swz = (lin & 7) * qn + (lin >> 3);
  int bm = swz % gridDim.x, bn = swz / gridDim.x;
  const char* Ab = (const char*)(A + (size_t)bm * 256 * Kd);
  const char* Bb = (const char*)(BT + (size_t)bn * 256 * Kd);
  size_t Kb = (size_t)Kd * 2;

  // staging geometry: 2 rounds x 16B per thread per operand; linear LDS dest,
  // inverse-swizzled global source.
  int L0 = wid * 1024 + lane * 16;
  int L1 = L0 + 8192;
  int sr0 = L0 >> 6, sr1 = L1 >> 6;
  int si0 = (L0 & 63) ^ ((sr0 & 3) << 4);
  int si1 = (L1 & 63) ^ ((sr1 & 3) << 4);
  const char* gA0 = Ab + (size_t)sr0 * Kb + si0;
  const char* gA1 = Ab + (size_t)sr1 * Kb + si1;
  const char* gB0 = Bb + (size_t)sr0 * Kb + si0;
  const char* gB1 = Bb + (size_t)sr1 * Kb + si1;

#define STAGE8(t, buf)                                                               \
  {                                                                                  \
    int kb = (t) * 64;                                                               \
    char* dA = smem + (buf) * 32768;                                                 \
    char* dB = dA + 16384;                                                           \
    __builtin_amdgcn_global_load_lds(                                                \
        (const __attribute__((address_space(1))) void*)(gA0 + kb),                   \
        (__attribute__((address_space(3))) void*)(dA + L0), 16, 0, 0);               \
    __builtin_amdgcn_global_load_lds(                                                \
        (const __attribute__((address_space(1))) void*)(gA1 + kb),                   \
        (__attribute__((address_space(3))) void*)(dA + L1), 16, 0, 0);               \
    __builtin_amdgcn_global_load_lds(                                                \
        (const __attribute__((address_space(1))) void*)(gB0 + kb),                   \
        (__attribute__((address_space(3))) void*)(dB + L0), 16, 0, 0);               \
    __builtin_amdgcn_global_load_lds(                                                \
        (const __attribute__((address_space(1))) void*)(gB1 + kb),                   \
        (__attribute__((address_space(3))) void*)(dB + L1), 16, 0, 0);               \
  }

  f32x4 acc[8][4];
#pragma unroll
  for (int i = 0; i < 8; i++)
#pragma unroll
    for (int j = 0; j < 4; j++) acc[i][j] = f32x4{0.f, 0.f, 0.f, 0.f};

  // read-side swizzled offsets
  int rA = wr * 128 + (lane & 15);
  int rB = wc * 64 + (lane & 15);
  int xA = (((lane >> 4) ^ rA) & 3) << 4;
  int xB = (((lane >> 4) ^ rB) & 3) << 4;

  int nt = Kd >> 5;
  STAGE8(0, 0);
  for (int t = 0; t < nt; ++t) {
    int c = t & 1;
    if (t + 1 < nt) {
      STAGE8(t + 1, c ^ 1);
      asm volatile("s_waitcnt vmcnt(4)" ::: "memory");
    } else {
      asm volatile("s_waitcnt vmcnt(0)" ::: "memory");
    }
    __builtin_amdgcn_sched_barrier(0);
    asm volatile("s_barrier" ::: "memory");
    const char* bA = smem + c * 32768;
    const char* bB = bA + 16384;
    bf16x8 b[4], a[4];
#pragma unroll
    for (int nf = 0; nf < 4; nf++)
      b[nf] = *(const bf16x8*)(bB + ((rB + nf * 16) << 6) + xB);
#pragma unroll
    for (int mf = 0; mf < 4; mf++)
      a[mf] = *(const bf16x8*)(bA + ((rA + mf * 16) << 6) + xA);
    __builtin_amdgcn_s_setprio(1);
#pragma unroll
    for (int mf = 0; mf < 4; mf++)
#pragma unroll
      for (int nf = 0; nf < 4; nf++)
        acc[mf][nf] = __builtin_amdgcn_mfma_f32_16x16x32_bf16(a[mf], b[nf], acc[mf][nf], 0, 0, 0);
    __builtin_amdgcn_s_setprio(0);
    asm volatile("s_barrier" ::: "memory");
#pragma unroll
    for (int mf = 0; mf < 4; mf++)
      a[mf] = *(const bf16x8*)(bA + ((rA + 64 + mf * 16) << 6) + xA);
    __builtin_amdgcn_s_setprio(1);
#pragma unroll
    for (int mf = 0; mf < 4; mf++)
#pragma unroll
      for (int nf = 0; nf < 4; nf++)
        acc[4 + mf][nf] = __builtin_amdgcn_mfma_f32_16x16x32_bf16(a[mf], b[nf], acc[4 + mf][nf], 0, 0, 0);
    __builtin_amdgcn_s_setprio(0);
    asm volatile("s_barrier" ::: "memory");
  }
#undef STAGE8

  int rw = (lane >> 4) * 4, cl = lane & 15;
#pragma unroll
  for (int mf = 0; mf < 8; mf++)
#pragma unroll
    for (int nf = 0; nf < 4; nf++) {
      int col = bn * 256 + wc * 64 + nf * 16 + cl;
#pragma unroll
      for (int r = 0; r < 4; r++) {
        int row = bm * 256 + wr * 128 + mf * 16 + rw + r;
        C[(size_t)row * ldc + col] = f2bf(acc[mf][nf][r]);
      }
    }
}

// ---------------- 2-phase 128x128 GEMM (kept for O-proj) ----------------
template <typename OutT>
__global__ __launch_bounds__(256) void k_gemm_bt(
    const unsigned short* __restrict__ A,   // M x K  bf16
    const unsigned short* __restrict__ BT,  // Npad x K  bf16
    OutT* __restrict__ C, int Kdim, int Ncols, int ldc) {
  __shared__ unsigned short sA[2][128 * 32];
  __shared__ unsigned short sB[2][128 * 32];
  int tid = threadIdx.x, wid = tid >> 6, lane = tid & 63;
  int gx = gridDim.x;
  int nwg = gx * gridDim.y;
  int lin = blockIdx.y * gx + blockIdx.x;
  int qn = nwg >> 3, rn = nwg & 7;
  int xcd = lin & 7, idx = lin >> 3;
  int swz = (xcd < rn ? xcd * (qn + 1) : rn * (qn + 1) + (xcd - rn) * qn) + idx;
  int bm = swz % gx, bn = swz / gx;
  const unsigned short* Ab = A + (size_t)bm * 128 * Kdim;
  const unsigned short* Bb = BT + (size_t)bn * 128 * Kdim;
  f32x4 acc[4][4];
#pragma unroll
  for (int i = 0; i < 4; i++)
#pragma unroll
    for (int j = 0; j < 4; j++) acc[i][j] = f32x4{0.f, 0.f, 0.f, 0.f};
  int wr = (wid >> 1) * 64, wc = (wid & 1) * 64;
  int srow = lane >> 2;
  int selem = (lane & 3) * 8;
  int rbase = lane & 15, koff = (lane >> 4) * 8;

#define G_STAGE(buf, kt)                                                             \
  {                                                                                  \
    _Pragma("unroll") for (int ch2 = 0; ch2 < 2; ++ch2) {                            \
      int chunk = wid * 2 + ch2;                                                     \
      const unsigned short* ga = Ab + (size_t)(chunk * 16 + srow) * Kdim + (kt) + selem; \
      const unsigned short* gb = Bb + (size_t)(chunk * 16 + srow) * Kdim + (kt) + selem; \
      __builtin_amdgcn_global_load_lds(                                              \
          (const __attribute__((address_space(1))) void*)ga,                         \
          (__attribute__((address_space(3))) void*)(&sA[buf][chunk * 512]), 16, 0, 0); \
      __builtin_amdgcn_global_load_lds(                                              \
          (const __attribute__((address_space(1))) void*)gb,                         \
          (__attribute__((address_space(3))) void*)(&sB[buf][chunk * 512]), 16, 0, 0); \
    }                                                                                \
  }

  int nt = Kdim >> 5;
  G_STAGE(0, 0);
  __syncthreads();
  int cur = 0;
  for (int t = 0; t < nt; ++t) {
    if (t + 1 < nt) G_STAGE(cur ^ 1, (t + 1) * 32);
    bf16x8 a[4], b[4];
#pragma unroll
    for (int i = 0; i < 4; i++)
      a[i] = *(const bf16x8*)(&sA[cur][(wr + i * 16 + rbase) * 32 + koff]);
#pragma unroll
    for (int j = 0; j < 4; j++)
      b[j] = *(const bf16x8*)(&sB[cur][(wc + j * 16 + rbase) * 32 + koff]);
#pragma unroll
    for (int i = 0; i < 4; i++)
#pragma unroll
      for (int j = 0; j < 4; j++)
        acc[i][j] = __builtin_amdgcn_mfma_f32_16x16x32_bf16(a[i], b[j], acc[i][j], 0, 0, 0);
    __syncthreads();
    cur ^= 1;
  }
#undef G_STAGE
  int rw = (lane >> 4) * 4, cl = lane & 15;
#pragma unroll
  for (int i = 0; i < 4; i++)
#pragma unroll
    for (int j = 0; j < 4; j++) {
      int col = bn * 128 + wc + j * 16 + cl;
      if (col < Ncols) {
#pragma unroll
        for (int r = 0; r < 4; r++) {
          int row = bm * 128 + wr + i * 16 + rw + r;
          float v = acc[i][j][r];
          if constexpr (sizeof(OutT) == 2)
            C[(size_t)row * ldc + col] = (OutT)f2bf(v);
          else
            C[(size_t)row * ldc + col] = v;
        }
      }
    }
}

// ---------------- RoPE in-place ----------------
__global__ void k_rope(unsigned short* __restrict__ qkv, const float* __restrict__ cosb,
                       const float* __restrict__ sinb) {
  int s = blockIdx.x;
  const float* cs = cosb + s * HD;
  const float* sn = sinb + s * HD;
  unsigned short* row = qkv + (size_t)s * NQKV;
  for (int idx = threadIdx.x; idx < (HQ + HKV) * 32; idx += blockDim.x) {
    int head = idx >> 5, dp = idx & 31;
    unsigned short* base = row + (head < HQ ? head * 64 : NQ + (head - HQ) * 64);
    float x1 = bf2f(base[dp]), x2 = bf2f(base[dp + 32]);
    float o1 = x1 * cs[dp] - x2 * sn[dp];
    float o2 = x2 * cs[dp + 32] + x1 * sn[dp + 32];
    base[dp] = f2bf(o1);
    base[dp + 32] = f2bf(o2);
  }
}

// ---------------- V transpose: qkv V cols -> vt[hkv][d][s] ----------------
__global__ void k_vtrans(const unsigned short* __restrict__ qkv, unsigned short* __restrict__ vt) {
  __shared__ unsigned short tile[64 * 66];
  int st = blockIdx.x, hk = blockIdx.y;
  int s0 = st * 64, t = threadIdx.x;
#pragma unroll
  for (int i = 0; i < 16; i++) {
    int e = i * 256 + t;
    int sl = e >> 6, d = e & 63;
    tile[d * 66 + sl] = qkv[(size_t)(s0 + sl) * NQKV + NQ + NKV + hk * 64 + d];
  }
  __syncthreads();
#pragma unroll
  for (int i = 0; i < 16; i++) {
    int e = i * 256 + t;
    int d = e >> 6, sl = e & 63;
    vt[(size_t)(hk * 64 + d) * SEQ + s0 + sl] = tile[d * 66 + sl];
  }
}

// ---------------- Flash attention: swapped-operand 32x32x16, P in registers ----------------
__global__ __launch_bounds__(256) void k_attn(
    const unsigned short* __restrict__ qkv, const unsigned short* __restrict__ vt,
    unsigned short* __restrict__ out) {
  __shared__ unsigned short smem[16384];  // 32KB: K dbuf [2][64*64] @0, V dbuf @8192
  int tid = threadIdx.x, wid = tid >> 6, lane = tid & 63;
  int head = blockIdx.x, qt = blockIdx.y;
  int hkv = head >> 3;
  int q = lane & 31, h = lane >> 5;
  int q0w = qt * 128 + wid * 32;
  const float SL2 = 0.125f * 1.44269504f;  // scale * log2(e)

  bf16x8 qf[4];
  {
    const unsigned short* qrow = qkv + (size_t)(q0w + q) * NQKV + head * 64 + h * 8;
#pragma unroll
    for (int ks = 0; ks < 4; ks++) qf[ks] = *(const bf16x8*)(qrow + ks * 16);
  }

  int r8 = lane >> 3;
  int srcslot = ((lane & 7) ^ r8) * 16;
  int sw = q & 7;

#define STAGE_KV(buf, kv)                                                            \
  {                                                                                  \
    _Pragma("unroll") for (int ch = 0; ch < 2; ++ch) {                               \
      int r0 = (wid * 2 + ch) * 8;                                                   \
      const char* gk =                                                               \
          (const char*)(qkv + (size_t)((kv) + r0 + r8) * NQKV + NQ + hkv * 64) +     \
          srcslot;                                                                   \
      __builtin_amdgcn_global_load_lds(                                              \
          (const __attribute__((address_space(1))) void*)gk,                         \
          (__attribute__((address_space(3))) void*)(smem + (buf)*4096 + r0 * 64),    \
          16, 0, 0);                                                                 \
      const char* gv =                                                               \
          (const char*)(vt + (size_t)(hkv * 64 + r0 + r8) * SEQ + (kv)) + srcslot;   \
      __builtin_amdgcn_global_load_lds(                                              \
          (const __attribute__((address_space(1))) void*)gv,                         \
          (__attribute__((address_space(3))) void*)(smem + 8192 + (buf)*4096 +       \
                                                    r0 * 64),                        \
          16, 0, 0);                                                                 \
    }                                                                                \
  }

  f32x16 o0, o1;
#pragma unroll
  for (int r = 0; r < 16; r++) { o0[r] = 0.f; o1[r] = 0.f; }
  float m = -3e38f, lp = 0.f;

  STAGE_KV(0, 0);
  __syncthreads();
  int cur = 0;

  for (int kvt = 0; kvt < SEQ / 64; ++kvt) {
    if (kvt + 1 < SEQ / 64) STAGE_KV(cur ^ 1, (kvt + 1) * 64);
    const char* kb = (const char*)(smem + cur * 4096);
    const char* vb = (const char*)(smem + 8192 + cur * 4096);

    f32x16 st0, st1;
#pragma unroll
    for (int r = 0; r < 16; r++) { st0[r] = 0.f; st1[r] = 0.f; }
    {
      bf16x8 kf[4];
#pragma unroll
      for (int ks = 0; ks < 4; ks++)
        kf[ks] = *(const bf16x8*)(kb + q * 128 + (((2 * ks + h) ^ sw) << 4));
#pragma unroll
      for (int ks = 0; ks < 4; ks++)
        st0 = __builtin_amdgcn_mfma_f32_32x32x16_bf16(kf[ks], qf[ks], st0, 0, 0, 0);
#pragma unroll
      for (int ks = 0; ks < 4; ks++)
        kf[ks] = *(const bf16x8*)(kb + (32 + q) * 128 + (((2 * ks + h) ^ sw) << 4));
#pragma unroll
      for (int ks = 0; ks < 4; ks++)
        st1 = __builtin_amdgcn_mfma_f32_32x32x16_bf16(kf[ks], qf[ks], st1, 0, 0, 0);
    }

    float tmx[16];
#pragma unroll
    for (int r = 0; r < 16; r++) tmx[r] = fmaxf(st0[r], st1[r]);
#pragma unroll
    for (int s = 8; s >= 1; s >>= 1)
#pragma unroll
      for (int r = 0; r < 8; r++)
        if (r < s) tmx[r] = fmaxf(tmx[r], tmx[r + s]);
    float mx = fmaxf(tmx[0], __shfl_xor(tmx[0], 32, 64));
    float t2 = mx * SL2;

    if (__any(t2 > m + 8.f)) {
      float mn = fmaxf(m, t2);
      float corr = exp2_hw(m - mn);
      m = mn;
      lp *= corr;
#pragma unroll
      for (int r = 0; r < 16; r++) { o0[r] *= corr; o1[r] *= corr; }
    }

    float psa[4] = {0.f, 0.f, 0.f, 0.f};
#pragma unroll
    for (int r = 0; r < 16; r++) {
      float e0 = exp2_hw(fmaf(st0[r], SL2, -m));
      float e1 = exp2_hw(fmaf(st1[r], SL2, -m));
      st0[r] = e0; st1[r] = e1;
      psa[r & 3] += e0 + e1;
    }
    lp += (psa[0] + psa[1]) + (psa[2] + psa[3]);

    u32 pk[16];
#pragma unroll
    for (int w = 0; w < 8; w++) {
      pk[w] = cvt_pk_bf16(st0[2 * w], st0[2 * w + 1]);
      pk[8 + w] = cvt_pk_bf16(st1[2 * w], st1[2 * w + 1]);
    }

    bf16x8 pf[4];
#pragma unroll
    for (int ks = 0; ks < 4; ks++) {
      int base = 8 * (ks >> 1) + 4 * (ks & 1);
      u32 wA0 = pk[base], wA1 = pk[base + 1], wB0 = pk[base + 2], wB1 = pk[base + 3];
      u32 keep0 = h ? wB0 : wA0, keep1 = h ? wB1 : wA1;
      u32 send0 = h ? wA0 : wB0, send1 = h ? wA1 : wB1;
      u32 rc0 = (u32)__shfl_xor((int)send0, 32, 64);
      u32 rc1 = (u32)__shfl_xor((int)send1, 32, 64);
      union { u32 w[4]; bf16x8 v; } u;
      u.w[0] = h ? rc0 : keep0;
      u.w[1] = h ? rc1 : keep1;
      u.w[2] = h ? keep0 : rc0;
      u.w[3] = h ? keep1 : rc1;
      pf[ks] = u.v;
    }

    {
      bf16x8 vf[4];
#pragma unroll
      for (int ks = 0; ks < 4; ks++)
        vf[ks] = *(const bf16x8*)(vb + q * 128 + (((2 * ks + h) ^ sw) << 4));
#pragma unroll
      for (int ks = 0; ks < 4; ks++)
        o0 = __builtin_amdgcn_mfma_f32_32x32x16_bf16(vf[ks], pf[ks], o0, 0, 0, 0);
#pragma unroll
      for (int ks = 0; ks < 4; ks++)
        vf[ks] = *(const bf16x8*)(vb + (32 + q) * 128 + (((2 * ks + h) ^ sw) << 4));
#pragma unroll
      for (int ks = 0; ks < 4; ks++)
        o1 = __builtin_amdgcn_mfma_f32_32x32x16_bf16(vf[ks], pf[ks], o1, 0, 0, 0);
    }

    __syncthreads();
    cur ^= 1;
  }

  float lpt = lp + __shfl_xor(lp, 32, 64);
  float inv = 1.0f / lpt;

  unsigned short* ot = smem + wid * (32 * 72);
#pragma unroll
  for (int w = 0; w < 8; w++) {
    int reg = 2 * w;
    int dbase = (reg & 3) + 8 * (reg >> 2) + 4 * h;
    u32 p0 = cvt_pk_bf16(o0[reg] * inv, o0[reg + 1] * inv);
    u32 p1 = cvt_pk_bf16(o1[reg] * inv, o1[reg + 1] * inv);
    *(u32*)(ot + q * 72 + dbase) = p0;
    *(u32*)(ot + q * 72 + 32 + dbase) = p1;
  }
  __syncthreads();
  int row = lane >> 1, halfc = lane & 1;
  const unsigned short* src = ot + row * 72 + halfc * 32;
  unsigned short* dst = out + (size_t)(q0w + row) * NQ + head * 64 + halfc * 32;
#pragma unroll
  for (int c = 0; c < 4; c++)
    *(bf16x8*)(dst + c * 8) = *(const bf16x8*)(src + c * 8);
#undef STAGE_KV
}

// ---------------- launch ----------------
extern "C" void kernel_launch(void* const* d_in, const int* in_sizes, int n_in,
                              void* d_out, int out_size, void* d_ws, size_t ws_size,
                              hipStream_t stream) {
  const float* hidden = (const float*)d_in[0];
  const float* cosb = (const float*)d_in[1];
  const float* sinb = (const float*)d_in[2];
  const float* wq = (const float*)d_in[3];
  const float* wk = (const float*)d_in[4];
  const float* wv = (const float*)d_in[5];
  const float* wo = (const float*)d_in[6];
  float* out = (float*)d_out;

  unsigned short* hb = (unsigned short*)d_ws;               // 2048*5760
  unsigned short* qkv = hb + (size_t)SEQ * INSZ;            // 2048*5120
  unsigned short* wqkvT = qkv + (size_t)SEQ * NQKV;         // 5120*5760
  unsigned short* woT = wqkvT + (size_t)NQKV * INSZ;        // 2944*4096
  unsigned short* vt = woT + (size_t)HIDP * NQ;             // 512*2048
  unsigned short* attn = vt + (size_t)NKV * SEQ;            // 2048*4096

  k_convert<<<dim3(1024), dim3(256), 0, stream>>>(hidden, hb, SEQ * INSZ);
  k_tconv<<<dim3(INSZ / 64, NQ / 32), dim3(256), 0, stream>>>(wq, wqkvT, INSZ, NQ);
  k_tconv<<<dim3(INSZ / 64, NKV / 32), dim3(256), 0, stream>>>(
      wk, wqkvT + (size_t)NQ * INSZ, INSZ, NKV);
  k_tconv<<<dim3(INSZ / 64, NKV / 32), dim3(256), 0, stream>>>(
      wv, wqkvT + (size_t)(NQ + NKV) * INSZ, INSZ, NKV);
  k_tconv<<<dim3(NQ / 64, HIDP / 32), dim3(256), 0, stream>>>(wo, woT, NQ, HID);

  // QKV projection: 8-phase-class 256x256 kernel (8 M-tiles x 20 N-tiles = 160 blocks)
  k_gemm8<<<dim3(SEQ / 256, NQKV / 256), dim3(512), 0, stream>>>(
      hb, wqkvT, qkv, INSZ, NQKV);
  k_rope<<<dim3(SEQ), dim3(256), 0, stream>>>(qkv, cosb, sinb);
  k_vtrans<<<dim3(SEQ / 64, HKV), dim3(256), 0, stream>>>(qkv, vt);
  k_attn<<<dim3(HQ, SEQ / 128), dim3(256), 0, stream>>>(qkv, vt, attn);
  k_gemm_bt<float><<<dim3(SEQ / 128, (HID + 127) / 128), dim3(256), 0, stream>>>(
      attn, woT, out, NQ, HID, HID);
}